// Round 7
// baseline (387.762 us; speedup 1.0000x reference)
//
#include <hip/hip_runtime.h>
#include <cmath>

// SSIM loss, vertical-first row-sliding kernel, merged 3D+2D dispatch.
// Round-7 structure: single-buffer 5-channel LDS (10.5 KB) with
// write|barrier|read|barrier per output row, BAND=16, grid = 2176 uniform
// blocks (2048 3D + 128 2D, each 26 steps), __launch_bounds__(256,8)
// -> 8 blocks/CU resident (32 waves/CU) to hide LDS/barrier latency.
// Block = 256 threads, each owns 2 adjacent columns; all math in f32x2
// ext-vectors (v_pk_*_f32). LDS stores vertical-blurred channels per
// column-PAIR: A4=(m1.x,m1.y,m2.x,m2.y) B4=(xx.x,xx.y,yy.x,yy.y) Z2=zz pair;
// horizontal taps = 7 slot reads at 16B lane stride (conflict-free) with
// compile-time packed coefficient pairs.

#define WSZ 11
#define IMG 512
#define SLICE (IMG * IMG)
#define BAND 16
#define TST (BAND + 10)        // 26 row steps per band

typedef float f32x2 __attribute__((ext_vector_type(2)));
typedef float f32x4 __attribute__((ext_vector_type(4)));

struct G11 { float w[WSZ]; };

__global__ __launch_bounds__(256, 8)
void ssim_pk_kernel(const float* __restrict__ A3, const float* __restrict__ B3,
                    const float* __restrict__ A2, const float* __restrict__ B2,
                    double* __restrict__ acc, G11 gw)
{
    __shared__ f32x4 A4[262];   // (m1,m2) pairs, 3-slot pad each side
    __shared__ f32x4 B4[262];   // (xx,yy) pairs
    __shared__ f32x2 Z2[262];   // zz pairs
    __shared__ float bsum[4];

    const int tx = threadIdx.x;    // 0..255 = column pair index
    const int x0 = tx * 2;

    // decode work unit: [0,2048) = 3D slice-bands, [2048,2176) = 2D bands
    const int unit = blockIdx.x;
    const float* Ap;
    const float* Bp;
    double* accp;
    int y0;
    if (unit < 2048) {
        int slice = unit >> 5;
        int band  = unit & 31;
        Ap = A3 + (long)slice * SLICE;
        Bp = B3 + (long)slice * SLICE;
        accp = acc + 0;
        y0 = band * BAND;
    } else {
        int uu = unit - 2048;
        int img  = uu >> 5;
        int band = uu & 31;
        Ap = A2 + (long)img * SLICE;
        Bp = B2 + (long)img * SLICE;
        accp = acc + 1;
        y0 = band * BAND;
    }

    // zero pads: pair slots 0..2 and 259..261
    if (tx < 3) {
        f32x4 z4 = {0.f, 0.f, 0.f, 0.f};
        f32x2 z2 = {0.f, 0.f};
        A4[tx] = z4; A4[259 + tx] = z4;
        B4[tx] = z4; B4[259 + tx] = z4;
        Z2[tx] = z2; Z2[259 + tx] = z2;
    }

    // 11-slot register ring of raw (a,b) pairs, statically indexed (unroll-11)
    f32x2 ra[11], rb[11];
    #pragma unroll
    for (int i = 0; i < 11; i++) { ra[i] = (f32x2){0.f, 0.f}; rb[i] = (f32x2){0.f, 0.f}; }

    float sum = 0.f;

    // prefetch first input row (r = y0 - 5)
    f32x2 aN = {0.f, 0.f}, bN = {0.f, 0.f};
    {
        int r = y0 - 5;
        if (r >= 0 && r < IMG) {
            aN = *(const f32x2*)&Ap[(long)r * IMG + x0];
            bN = *(const f32x2*)&Bp[(long)r * IMG + x0];
        }
    }

    const f32x2 C1v = {1e-4f, 1e-4f};
    const f32x2 C2v = {9e-4f, 9e-4f};

    for (int t0 = 0; t0 < TST; t0 += 11) {
        #pragma unroll
        for (int u = 0; u < 11; u++) {
            const int t = t0 + u;
            if (t < TST) {                    // block-uniform
                ra[u] = aN;
                rb[u] = bN;

                // prefetch next row (block-uniform guard)
                {
                    int rn = y0 - 4 + t;
                    aN = (f32x2){0.f, 0.f}; bN = (f32x2){0.f, 0.f};
                    if ((t + 1 < TST) && rn >= 0 && rn < IMG) {
                        aN = *(const f32x2*)&Ap[(long)rn * IMG + x0];
                        bN = *(const f32x2*)&Bp[(long)rn * IMG + x0];
                    }
                }

                if (t >= 10) {                // output row o = y0 + t - 10
                    // vertical 11-tap (packed): slot (u+1+j)%11 = row o-5+j
                    f32x2 m1 = {0.f, 0.f}, m2 = m1, xx = m1, yy = m1, zz = m1;
                    #pragma unroll
                    for (int j = 0; j < 11; j++) {
                        const int s = (u + 1 + j) % 11;     // compile-time
                        const f32x2 g2 = {gw.w[j], gw.w[j]};
                        f32x2 a = ra[s], b = rb[s];
                        f32x2 ga = g2 * a, gb = g2 * b;
                        m1 += ga; m2 += gb;
                        xx += ga * a; yy += gb * b; zz += ga * b;
                    }
                    A4[3 + tx] = __builtin_shufflevector(m1, m2, 0, 1, 2, 3);
                    B4[3 + tx] = __builtin_shufflevector(xx, yy, 0, 1, 2, 3);
                    Z2[3 + tx] = zz;
                    __syncthreads();          // writes visible before reads

                    // horizontal 11-tap over 7 pair slots, packed coefficients.
                    // slot jj holds cols (x0-6+2jj, x0-5+2jj); for output pair
                    // (x0, x0+1): e0 coeffs (g[2jj-1], g[2jj-2]), e1 (g[2jj], g[2jj-1]).
                    f32x2 OM1 = {0.f, 0.f}, OM2 = OM1, OXX = OM1, OYY = OM1, OZZ = OM1;
                    {   // jj = 0: only e1 with (g0, 0)
                        f32x4 pa = A4[tx], pb = B4[tx];
                        f32x2 pz = Z2[tx];
                        const f32x2 c = {gw.w[0], 0.f};
                        OM1 += c * __builtin_shufflevector(pa, pa, 1, 1);
                        OM2 += c * __builtin_shufflevector(pa, pa, 3, 3);
                        OXX += c * __builtin_shufflevector(pb, pb, 1, 1);
                        OYY += c * __builtin_shufflevector(pb, pb, 3, 3);
                        OZZ += c * __builtin_shufflevector(pz, pz, 1, 1);
                    }
                    #pragma unroll
                    for (int jj = 1; jj <= 5; jj++) {
                        f32x4 pa = A4[tx + jj], pb = B4[tx + jj];
                        f32x2 pz = Z2[tx + jj];
                        const f32x2 cA = {gw.w[2 * jj - 1], gw.w[2 * jj - 2]};
                        const f32x2 cB = {gw.w[2 * jj],     gw.w[2 * jj - 1]};
                        OM1 += cA * __builtin_shufflevector(pa, pa, 0, 0)
                             + cB * __builtin_shufflevector(pa, pa, 1, 1);
                        OM2 += cA * __builtin_shufflevector(pa, pa, 2, 2)
                             + cB * __builtin_shufflevector(pa, pa, 3, 3);
                        OXX += cA * __builtin_shufflevector(pb, pb, 0, 0)
                             + cB * __builtin_shufflevector(pb, pb, 1, 1);
                        OYY += cA * __builtin_shufflevector(pb, pb, 2, 2)
                             + cB * __builtin_shufflevector(pb, pb, 3, 3);
                        OZZ += cA * __builtin_shufflevector(pz, pz, 0, 0)
                             + cB * __builtin_shufflevector(pz, pz, 1, 1);
                    }
                    {   // jj = 6: only e0 with (0, g10)
                        f32x4 pa = A4[tx + 6], pb = B4[tx + 6];
                        f32x2 pz = Z2[tx + 6];
                        const f32x2 c = {0.f, gw.w[10]};
                        OM1 += c * __builtin_shufflevector(pa, pa, 0, 0);
                        OM2 += c * __builtin_shufflevector(pa, pa, 2, 2);
                        OXX += c * __builtin_shufflevector(pb, pb, 0, 0);
                        OYY += c * __builtin_shufflevector(pb, pb, 2, 2);
                        OZZ += c * __builtin_shufflevector(pz, pz, 0, 0);
                    }
                    __syncthreads();          // reads done before next row's writes

                    // SSIM formula, packed where possible
                    f32x2 m1s = OM1 * OM1, m2s = OM2 * OM2, m12 = OM1 * OM2;
                    f32x2 s1 = OXX - m1s, s2 = OYY - m2s, s12 = OZZ - m12;
                    f32x2 d1 = m1s + m2s + C1v;
                    f32x2 d2 = s1 + s2 + C2v;
                    f32x2 num = (2.f * m12 + C1v) * (2.f * s12 + C2v) * (s12 + C2v);
                    float d3x = __builtin_amdgcn_sqrtf(s1.x) * __builtin_amdgcn_sqrtf(s2.x) + 9e-4f;
                    float d3y = __builtin_amdgcn_sqrtf(s1.y) * __builtin_amdgcn_sqrtf(s2.y) + 9e-4f;
                    sum += num.x * __builtin_amdgcn_rcpf(d1.x * d2.x * d3x);
                    sum += num.y * __builtin_amdgcn_rcpf(d1.y * d2.y * d3y);
                }
            }
        }
    }

    // block reduction: wave shuffle -> LDS -> one atomic per block
    for (int off = 32; off > 0; off >>= 1)
        sum += __shfl_down(sum, off, 64);
    if ((tx & 63) == 0) bsum[tx >> 6] = sum;
    __syncthreads();
    if (tx == 0) {
        float tot = bsum[0] + bsum[1] + bsum[2] + bsum[3];
        atomicAdd(accp, (double)tot);
    }
}

// b2 = mean over 16 depth slices of img2, vectorized float4 (BW-bound).
__global__ __launch_bounds__(256) void depth_mean4_kernel(
    const float4* __restrict__ img2, float4* __restrict__ b2)
{
    const int per = SLICE / 4;                       // 65536 float4 per slice
    int idx = blockIdx.x * 256 + threadIdx.x;        // 0 .. 4*per-1
    int b = idx >> 16;
    int p = idx & (per - 1);
    const float4* src = img2 + (long)b * 16 * per + p;
    float sx = 0.f, sy = 0.f, sz = 0.f, sw = 0.f;
    #pragma unroll
    for (int d = 0; d < 16; d++) {
        float4 v = src[(long)d * per];
        sx += v.x; sy += v.y; sz += v.z; sw += v.w;
    }
    float4 o; o.x = sx * 0.0625f; o.y = sy * 0.0625f; o.z = sz * 0.0625f; o.w = sw * 0.0625f;
    b2[idx] = o;
}

__global__ void finalize_kernel(const double* __restrict__ acc, float* __restrict__ out)
{
    double loss3 = 1.0 - acc[0] / (64.0 * (double)SLICE);
    double loss2 = 1.0 - acc[1] / (4.0 * (double)SLICE);
    out[0] = (float)(loss3 + loss2);
}

extern "C" void kernel_launch(void* const* d_in, const int* in_sizes, int n_in,
                              void* d_out, int out_size, void* d_ws, size_t ws_size,
                              hipStream_t stream)
{
    const float* img1_3d = (const float*)d_in[0];   // [4,1,16,512,512] -> 64 slices
    const float* img1_2d = (const float*)d_in[1];   // [4,1,512,512]
    const float* img2    = (const float*)d_in[2];   // [4,1,16,512,512]
    float* out = (float*)d_out;

    double* acc = (double*)d_ws;                    // [0]=3D sum, [1]=2D sum
    float*  b2  = (float*)((char*)d_ws + 256);      // 4 MB depth-mean buffer

    // Gaussian weights, like cv2.getGaussianKernel(11, 1.5) in double.
    G11 gw;
    {
        double g[WSZ], s = 0.0;
        for (int i = 0; i < WSZ; i++) {
            double xx = (double)i - (WSZ - 1) / 2.0;
            g[i] = std::exp(-(xx * xx) / (2.0 * 1.5 * 1.5));
            s += g[i];
        }
        for (int i = 0; i < WSZ; i++) gw.w[i] = (float)(g[i] / s);
    }

    hipMemsetAsync(acc, 0, 2 * sizeof(double), stream);

    // depth mean of img2 -> b2 (68 MB, ~12 us)
    depth_mean4_kernel<<<(4 * SLICE / 4) / 256, 256, 0, stream>>>(
        (const float4*)img2, (float4*)b2);

    // merged SSIM: 2048 3D bands + 128 2D bands = 2176 uniform blocks
    // (~8.5 blocks/CU at the 8-block VGPR-limited residency).
    ssim_pk_kernel<<<2176, 256, 0, stream>>>(img1_3d, img2, img1_2d, b2, acc, gw);

    finalize_kernel<<<1, 1, 0, stream>>>(acc, out);
}

// Round 8
// 234.235 us; speedup vs baseline: 1.6554x; 1.6554x over previous
//
#include <hip/hip_runtime.h>
#include <cmath>

// SSIM loss, vertical-first row-sliding kernel, merged 3D+2D dispatch.
// Round-8 = round-6 structure (proven: 48 VGPR, 21 KB LDS, 0 bank conflicts)
// with residency raised from 5 to 7 blocks/CU:
//   __launch_bounds__(256,7) -> VGPR cap 73 (ring needs ~48: SAFE; caps <73
//   spill catastrophically - round 3/5/7 lesson), grid = 1792 = 7*256 blocks:
//   3D = 64 slices x 24 bands (16x22 rows + 8x20 rows), 2D = 4 imgs x 64x8.
// Block = 256 threads, each owns 2 adjacent columns; all math in f32x2
// ext-vectors (v_pk_*_f32). Double-buffered LDS of vertical-blurred channels
// per column-PAIR: A4=(m1.x,m1.y,m2.x,m2.y) B4=(xx.x,xx.y,yy.x,yy.y) Z2=zz;
// horizontal taps = 7 slot reads at 16B lane stride (conflict-free) with
// compile-time packed coefficient pairs. One barrier per output row.

#define WSZ 11
#define IMG 512
#define SLICE (IMG * IMG)

typedef float f32x2 __attribute__((ext_vector_type(2)));
typedef float f32x4 __attribute__((ext_vector_type(4)));

struct G11 { float w[WSZ]; };

__global__ __launch_bounds__(256, 7)
void ssim_pk_kernel(const float* __restrict__ A3, const float* __restrict__ B3,
                    const float* __restrict__ A2, const float* __restrict__ B2,
                    double* __restrict__ acc, G11 gw)
{
    __shared__ f32x4 A4[2][262];   // (m1,m2) pairs, 3-slot pad each side
    __shared__ f32x4 B4[2][262];   // (xx,yy) pairs
    __shared__ f32x2 Z2[2][262];   // zz pairs
    __shared__ float bsum[4];

    const int tx = threadIdx.x;    // 0..255 = column pair index
    const int x0 = tx * 2;

    // decode work unit: [0,1536) = 3D slice-bands, [1536,1792) = 2D bands
    const int unit = blockIdx.x;
    const float* Ap;
    const float* Bp;
    double* accp;
    int y0, TST;
    if (unit < 1536) {
        int slice = unit / 24;
        int band  = unit - slice * 24;
        Ap = A3 + (long)slice * SLICE;
        Bp = B3 + (long)slice * SLICE;
        accp = acc + 0;
        if (band < 16) { y0 = band * 22;              TST = 22 + 10; }
        else           { y0 = 352 + (band - 16) * 20; TST = 20 + 10; }
    } else {
        int uu = unit - 1536;
        int img  = uu >> 6;
        int band = uu & 63;
        Ap = A2 + (long)img * SLICE;
        Bp = B2 + (long)img * SLICE;
        accp = acc + 1;
        y0 = band * 8;
        TST = 8 + 10;
    }

    // zero pads: pair slots 0..2 and 259..261, both buffers
    if (tx < 3) {
        f32x4 z4 = {0.f, 0.f, 0.f, 0.f};
        f32x2 z2 = {0.f, 0.f};
        A4[0][tx] = z4; A4[1][tx] = z4; A4[0][259 + tx] = z4; A4[1][259 + tx] = z4;
        B4[0][tx] = z4; B4[1][tx] = z4; B4[0][259 + tx] = z4; B4[1][259 + tx] = z4;
        Z2[0][tx] = z2; Z2[1][tx] = z2; Z2[0][259 + tx] = z2; Z2[1][259 + tx] = z2;
    }

    // 11-slot register ring of raw (a,b) pairs, statically indexed (unroll-11)
    f32x2 ra[11], rb[11];
    #pragma unroll
    for (int i = 0; i < 11; i++) { ra[i] = (f32x2){0.f, 0.f}; rb[i] = (f32x2){0.f, 0.f}; }

    float sum = 0.f;

    // prefetch first input row (r = y0 - 5)
    f32x2 aN = {0.f, 0.f}, bN = {0.f, 0.f};
    {
        int r = y0 - 5;
        if (r >= 0 && r < IMG) {
            aN = *(const f32x2*)&Ap[(long)r * IMG + x0];
            bN = *(const f32x2*)&Bp[(long)r * IMG + x0];
        }
    }

    const f32x2 C1v = {1e-4f, 1e-4f};
    const f32x2 C2v = {9e-4f, 9e-4f};

    for (int t0 = 0; t0 < TST; t0 += 11) {
        #pragma unroll
        for (int u = 0; u < 11; u++) {
            const int t = t0 + u;
            if (t < TST) {                    // block-uniform
                ra[u] = aN;
                rb[u] = bN;

                // prefetch next row (block-uniform guard)
                {
                    int rn = y0 - 4 + t;
                    aN = (f32x2){0.f, 0.f}; bN = (f32x2){0.f, 0.f};
                    if ((t + 1 < TST) && rn >= 0 && rn < IMG) {
                        aN = *(const f32x2*)&Ap[(long)rn * IMG + x0];
                        bN = *(const f32x2*)&Bp[(long)rn * IMG + x0];
                    }
                }

                if (t >= 10) {                // output row o = y0 + t - 10
                    // vertical 11-tap (packed): slot (u+1+j)%11 = row o-5+j
                    f32x2 m1 = {0.f, 0.f}, m2 = m1, xx = m1, yy = m1, zz = m1;
                    #pragma unroll
                    for (int j = 0; j < 11; j++) {
                        const int s = (u + 1 + j) % 11;     // compile-time
                        const f32x2 g2 = {gw.w[j], gw.w[j]};
                        f32x2 a = ra[s], b = rb[s];
                        f32x2 ga = g2 * a, gb = g2 * b;
                        m1 += ga; m2 += gb;
                        xx += ga * a; yy += gb * b; zz += ga * b;
                    }
                    const int buf = t & 1;
                    A4[buf][3 + tx] = __builtin_shufflevector(m1, m2, 0, 1, 2, 3);
                    B4[buf][3 + tx] = __builtin_shufflevector(xx, yy, 0, 1, 2, 3);
                    Z2[buf][3 + tx] = zz;
                    __syncthreads();

                    // horizontal 11-tap over 7 pair slots, packed coefficients.
                    // slot jj holds cols (x0-6+2jj, x0-5+2jj); for output pair
                    // (x0, x0+1): e0 coeffs (g[2jj-1], g[2jj-2]), e1 (g[2jj], g[2jj-1]).
                    f32x2 OM1 = {0.f, 0.f}, OM2 = OM1, OXX = OM1, OYY = OM1, OZZ = OM1;
                    {   // jj = 0: only e1 with (g0, 0)
                        f32x4 pa = A4[buf][tx], pb = B4[buf][tx];
                        f32x2 pz = Z2[buf][tx];
                        const f32x2 c = {gw.w[0], 0.f};
                        OM1 += c * __builtin_shufflevector(pa, pa, 1, 1);
                        OM2 += c * __builtin_shufflevector(pa, pa, 3, 3);
                        OXX += c * __builtin_shufflevector(pb, pb, 1, 1);
                        OYY += c * __builtin_shufflevector(pb, pb, 3, 3);
                        OZZ += c * __builtin_shufflevector(pz, pz, 1, 1);
                    }
                    #pragma unroll
                    for (int jj = 1; jj <= 5; jj++) {
                        f32x4 pa = A4[buf][tx + jj], pb = B4[buf][tx + jj];
                        f32x2 pz = Z2[buf][tx + jj];
                        const f32x2 cA = {gw.w[2 * jj - 1], gw.w[2 * jj - 2]};
                        const f32x2 cB = {gw.w[2 * jj],     gw.w[2 * jj - 1]};
                        OM1 += cA * __builtin_shufflevector(pa, pa, 0, 0)
                             + cB * __builtin_shufflevector(pa, pa, 1, 1);
                        OM2 += cA * __builtin_shufflevector(pa, pa, 2, 2)
                             + cB * __builtin_shufflevector(pa, pa, 3, 3);
                        OXX += cA * __builtin_shufflevector(pb, pb, 0, 0)
                             + cB * __builtin_shufflevector(pb, pb, 1, 1);
                        OYY += cA * __builtin_shufflevector(pb, pb, 2, 2)
                             + cB * __builtin_shufflevector(pb, pb, 3, 3);
                        OZZ += cA * __builtin_shufflevector(pz, pz, 0, 0)
                             + cB * __builtin_shufflevector(pz, pz, 1, 1);
                    }
                    {   // jj = 6: only e0 with (0, g10)
                        f32x4 pa = A4[buf][tx + 6], pb = B4[buf][tx + 6];
                        f32x2 pz = Z2[buf][tx + 6];
                        const f32x2 c = {0.f, gw.w[10]};
                        OM1 += c * __builtin_shufflevector(pa, pa, 0, 0);
                        OM2 += c * __builtin_shufflevector(pa, pa, 2, 2);
                        OXX += c * __builtin_shufflevector(pb, pb, 0, 0);
                        OYY += c * __builtin_shufflevector(pb, pb, 2, 2);
                        OZZ += c * __builtin_shufflevector(pz, pz, 0, 0);
                    }

                    // SSIM formula, packed where possible
                    f32x2 m1s = OM1 * OM1, m2s = OM2 * OM2, m12 = OM1 * OM2;
                    f32x2 s1 = OXX - m1s, s2 = OYY - m2s, s12 = OZZ - m12;
                    f32x2 d1 = m1s + m2s + C1v;
                    f32x2 d2 = s1 + s2 + C2v;
                    f32x2 num = (2.f * m12 + C1v) * (2.f * s12 + C2v) * (s12 + C2v);
                    float d3x = __builtin_amdgcn_sqrtf(s1.x) * __builtin_amdgcn_sqrtf(s2.x) + 9e-4f;
                    float d3y = __builtin_amdgcn_sqrtf(s1.y) * __builtin_amdgcn_sqrtf(s2.y) + 9e-4f;
                    sum += num.x * __builtin_amdgcn_rcpf(d1.x * d2.x * d3x);
                    sum += num.y * __builtin_amdgcn_rcpf(d1.y * d2.y * d3y);
                }
            }
        }
    }

    // block reduction: wave shuffle -> LDS -> one atomic per block
    for (int off = 32; off > 0; off >>= 1)
        sum += __shfl_down(sum, off, 64);
    if ((tx & 63) == 0) bsum[tx >> 6] = sum;
    __syncthreads();
    if (tx == 0) {
        float tot = bsum[0] + bsum[1] + bsum[2] + bsum[3];
        atomicAdd(accp, (double)tot);
    }
}

// b2 = mean over 16 depth slices of img2, vectorized float4 (BW-bound).
__global__ __launch_bounds__(256) void depth_mean4_kernel(
    const float4* __restrict__ img2, float4* __restrict__ b2)
{
    const int per = SLICE / 4;                       // 65536 float4 per slice
    int idx = blockIdx.x * 256 + threadIdx.x;        // 0 .. 4*per-1
    int b = idx >> 16;
    int p = idx & (per - 1);
    const float4* src = img2 + (long)b * 16 * per + p;
    float sx = 0.f, sy = 0.f, sz = 0.f, sw = 0.f;
    #pragma unroll
    for (int d = 0; d < 16; d++) {
        float4 v = src[(long)d * per];
        sx += v.x; sy += v.y; sz += v.z; sw += v.w;
    }
    float4 o; o.x = sx * 0.0625f; o.y = sy * 0.0625f; o.z = sz * 0.0625f; o.w = sw * 0.0625f;
    b2[idx] = o;
}

__global__ void finalize_kernel(const double* __restrict__ acc, float* __restrict__ out)
{
    double loss3 = 1.0 - acc[0] / (64.0 * (double)SLICE);
    double loss2 = 1.0 - acc[1] / (4.0 * (double)SLICE);
    out[0] = (float)(loss3 + loss2);
}

extern "C" void kernel_launch(void* const* d_in, const int* in_sizes, int n_in,
                              void* d_out, int out_size, void* d_ws, size_t ws_size,
                              hipStream_t stream)
{
    const float* img1_3d = (const float*)d_in[0];   // [4,1,16,512,512] -> 64 slices
    const float* img1_2d = (const float*)d_in[1];   // [4,1,512,512]
    const float* img2    = (const float*)d_in[2];   // [4,1,16,512,512]
    float* out = (float*)d_out;

    double* acc = (double*)d_ws;                    // [0]=3D sum, [1]=2D sum
    float*  b2  = (float*)((char*)d_ws + 256);      // 4 MB depth-mean buffer

    // Gaussian weights, like cv2.getGaussianKernel(11, 1.5) in double.
    G11 gw;
    {
        double g[WSZ], s = 0.0;
        for (int i = 0; i < WSZ; i++) {
            double xx = (double)i - (WSZ - 1) / 2.0;
            g[i] = std::exp(-(xx * xx) / (2.0 * 1.5 * 1.5));
            s += g[i];
        }
        for (int i = 0; i < WSZ; i++) gw.w[i] = (float)(g[i] / s);
    }

    hipMemsetAsync(acc, 0, 2 * sizeof(double), stream);

    // depth mean of img2 -> b2 (68 MB, ~12 us)
    depth_mean4_kernel<<<(4 * SLICE / 4) / 256, 256, 0, stream>>>(
        (const float4*)img2, (float4*)b2);

    // merged SSIM: 1536 3D bands (64 slices x (16x22 + 8x20 rows))
    // + 256 2D bands (4 imgs x 64x8 rows) = 1792 blocks = exactly 7/CU.
    ssim_pk_kernel<<<1792, 256, 0, stream>>>(img1_3d, img2, img1_2d, b2, acc, gw);

    finalize_kernel<<<1, 1, 0, stream>>>(acc, out);
}

// Round 9
// 106.013 us; speedup vs baseline: 3.6577x; 2.2095x over previous
//
#include <hip/hip_runtime.h>
#include <cmath>

// SSIM loss, vertical-first row-sliding kernel, merged 3D+2D dispatch.
// Round-9 = round-6 kernel binary (launch_bounds(256,5): 48 VGPR, no spill,
// 21 KB LDS, 0 bank conflicts) + 1792-block grid (= exactly 7 blocks/CU,
// the LDS-limited residency cap). Round-8 lesson: waves-min >= 6 forces the
// allocator under 48 VGPR and spills catastrophically; launch_bounds only
// constrains the allocator, residency comes from actual usage + grid size.
// Block = 256 threads, each owns 2 adjacent columns; all math in f32x2
// ext-vectors (v_pk_*_f32). Double-buffered LDS of vertical-blurred channels
// per column-PAIR: A4=(m1.x,m1.y,m2.x,m2.y) B4=(xx.x,xx.y,yy.x,yy.y) Z2=zz;
// horizontal taps = 7 slot reads at 16B lane stride (conflict-free) with
// compile-time packed coefficient pairs. One barrier per output row.

#define WSZ 11
#define IMG 512
#define SLICE (IMG * IMG)

typedef float f32x2 __attribute__((ext_vector_type(2)));
typedef float f32x4 __attribute__((ext_vector_type(4)));

struct G11 { float w[WSZ]; };

__global__ __launch_bounds__(256, 5)
void ssim_pk_kernel(const float* __restrict__ A3, const float* __restrict__ B3,
                    const float* __restrict__ A2, const float* __restrict__ B2,
                    double* __restrict__ acc, G11 gw)
{
    __shared__ f32x4 A4[2][262];   // (m1,m2) pairs, 3-slot pad each side
    __shared__ f32x4 B4[2][262];   // (xx,yy) pairs
    __shared__ f32x2 Z2[2][262];   // zz pairs
    __shared__ float bsum[4];

    const int tx = threadIdx.x;    // 0..255 = column pair index
    const int x0 = tx * 2;

    // decode work unit: [0,1536) = 3D slice-bands (24/slice: 16x22 + 8x20 rows),
    // [1536,1792) = 2D bands (4 imgs x 64 bands of 8 rows)
    const int unit = blockIdx.x;
    const float* Ap;
    const float* Bp;
    double* accp;
    int y0, TST;
    if (unit < 1536) {
        int slice = unit / 24;
        int band  = unit - slice * 24;
        Ap = A3 + (long)slice * SLICE;
        Bp = B3 + (long)slice * SLICE;
        accp = acc + 0;
        if (band < 16) { y0 = band * 22;              TST = 22 + 10; }
        else           { y0 = 352 + (band - 16) * 20; TST = 20 + 10; }
    } else {
        int uu = unit - 1536;
        int img  = uu >> 6;
        int band = uu & 63;
        Ap = A2 + (long)img * SLICE;
        Bp = B2 + (long)img * SLICE;
        accp = acc + 1;
        y0 = band * 8;
        TST = 8 + 10;
    }

    // zero pads: pair slots 0..2 and 259..261, both buffers
    if (tx < 3) {
        f32x4 z4 = {0.f, 0.f, 0.f, 0.f};
        f32x2 z2 = {0.f, 0.f};
        A4[0][tx] = z4; A4[1][tx] = z4; A4[0][259 + tx] = z4; A4[1][259 + tx] = z4;
        B4[0][tx] = z4; B4[1][tx] = z4; B4[0][259 + tx] = z4; B4[1][259 + tx] = z4;
        Z2[0][tx] = z2; Z2[1][tx] = z2; Z2[0][259 + tx] = z2; Z2[1][259 + tx] = z2;
    }

    // 11-slot register ring of raw (a,b) pairs, statically indexed (unroll-11)
    f32x2 ra[11], rb[11];
    #pragma unroll
    for (int i = 0; i < 11; i++) { ra[i] = (f32x2){0.f, 0.f}; rb[i] = (f32x2){0.f, 0.f}; }

    float sum = 0.f;

    // prefetch first input row (r = y0 - 5)
    f32x2 aN = {0.f, 0.f}, bN = {0.f, 0.f};
    {
        int r = y0 - 5;
        if (r >= 0 && r < IMG) {
            aN = *(const f32x2*)&Ap[(long)r * IMG + x0];
            bN = *(const f32x2*)&Bp[(long)r * IMG + x0];
        }
    }

    const f32x2 C1v = {1e-4f, 1e-4f};
    const f32x2 C2v = {9e-4f, 9e-4f};

    for (int t0 = 0; t0 < TST; t0 += 11) {
        #pragma unroll
        for (int u = 0; u < 11; u++) {
            const int t = t0 + u;
            if (t < TST) {                    // block-uniform
                ra[u] = aN;
                rb[u] = bN;

                // prefetch next row (block-uniform guard)
                {
                    int rn = y0 - 4 + t;
                    aN = (f32x2){0.f, 0.f}; bN = (f32x2){0.f, 0.f};
                    if ((t + 1 < TST) && rn >= 0 && rn < IMG) {
                        aN = *(const f32x2*)&Ap[(long)rn * IMG + x0];
                        bN = *(const f32x2*)&Bp[(long)rn * IMG + x0];
                    }
                }

                if (t >= 10) {                // output row o = y0 + t - 10
                    // vertical 11-tap (packed): slot (u+1+j)%11 = row o-5+j
                    f32x2 m1 = {0.f, 0.f}, m2 = m1, xx = m1, yy = m1, zz = m1;
                    #pragma unroll
                    for (int j = 0; j < 11; j++) {
                        const int s = (u + 1 + j) % 11;     // compile-time
                        const f32x2 g2 = {gw.w[j], gw.w[j]};
                        f32x2 a = ra[s], b = rb[s];
                        f32x2 ga = g2 * a, gb = g2 * b;
                        m1 += ga; m2 += gb;
                        xx += ga * a; yy += gb * b; zz += ga * b;
                    }
                    const int buf = t & 1;
                    A4[buf][3 + tx] = __builtin_shufflevector(m1, m2, 0, 1, 2, 3);
                    B4[buf][3 + tx] = __builtin_shufflevector(xx, yy, 0, 1, 2, 3);
                    Z2[buf][3 + tx] = zz;
                    __syncthreads();

                    // horizontal 11-tap over 7 pair slots, packed coefficients.
                    // slot jj holds cols (x0-6+2jj, x0-5+2jj); for output pair
                    // (x0, x0+1): e0 coeffs (g[2jj-1], g[2jj-2]), e1 (g[2jj], g[2jj-1]).
                    f32x2 OM1 = {0.f, 0.f}, OM2 = OM1, OXX = OM1, OYY = OM1, OZZ = OM1;
                    {   // jj = 0: only e1 with (g0, 0)
                        f32x4 pa = A4[buf][tx], pb = B4[buf][tx];
                        f32x2 pz = Z2[buf][tx];
                        const f32x2 c = {gw.w[0], 0.f};
                        OM1 += c * __builtin_shufflevector(pa, pa, 1, 1);
                        OM2 += c * __builtin_shufflevector(pa, pa, 3, 3);
                        OXX += c * __builtin_shufflevector(pb, pb, 1, 1);
                        OYY += c * __builtin_shufflevector(pb, pb, 3, 3);
                        OZZ += c * __builtin_shufflevector(pz, pz, 1, 1);
                    }
                    #pragma unroll
                    for (int jj = 1; jj <= 5; jj++) {
                        f32x4 pa = A4[buf][tx + jj], pb = B4[buf][tx + jj];
                        f32x2 pz = Z2[buf][tx + jj];
                        const f32x2 cA = {gw.w[2 * jj - 1], gw.w[2 * jj - 2]};
                        const f32x2 cB = {gw.w[2 * jj],     gw.w[2 * jj - 1]};
                        OM1 += cA * __builtin_shufflevector(pa, pa, 0, 0)
                             + cB * __builtin_shufflevector(pa, pa, 1, 1);
                        OM2 += cA * __builtin_shufflevector(pa, pa, 2, 2)
                             + cB * __builtin_shufflevector(pa, pa, 3, 3);
                        OXX += cA * __builtin_shufflevector(pb, pb, 0, 0)
                             + cB * __builtin_shufflevector(pb, pb, 1, 1);
                        OYY += cA * __builtin_shufflevector(pb, pb, 2, 2)
                             + cB * __builtin_shufflevector(pb, pb, 3, 3);
                        OZZ += cA * __builtin_shufflevector(pz, pz, 0, 0)
                             + cB * __builtin_shufflevector(pz, pz, 1, 1);
                    }
                    {   // jj = 6: only e0 with (0, g10)
                        f32x4 pa = A4[buf][tx + 6], pb = B4[buf][tx + 6];
                        f32x2 pz = Z2[buf][tx + 6];
                        const f32x2 c = {0.f, gw.w[10]};
                        OM1 += c * __builtin_shufflevector(pa, pa, 0, 0);
                        OM2 += c * __builtin_shufflevector(pa, pa, 2, 2);
                        OXX += c * __builtin_shufflevector(pb, pb, 0, 0);
                        OYY += c * __builtin_shufflevector(pb, pb, 2, 2);
                        OZZ += c * __builtin_shufflevector(pz, pz, 0, 0);
                    }

                    // SSIM formula, packed where possible
                    f32x2 m1s = OM1 * OM1, m2s = OM2 * OM2, m12 = OM1 * OM2;
                    f32x2 s1 = OXX - m1s, s2 = OYY - m2s, s12 = OZZ - m12;
                    f32x2 d1 = m1s + m2s + C1v;
                    f32x2 d2 = s1 + s2 + C2v;
                    f32x2 num = (2.f * m12 + C1v) * (2.f * s12 + C2v) * (s12 + C2v);
                    float d3x = __builtin_amdgcn_sqrtf(s1.x) * __builtin_amdgcn_sqrtf(s2.x) + 9e-4f;
                    float d3y = __builtin_amdgcn_sqrtf(s1.y) * __builtin_amdgcn_sqrtf(s2.y) + 9e-4f;
                    sum += num.x * __builtin_amdgcn_rcpf(d1.x * d2.x * d3x);
                    sum += num.y * __builtin_amdgcn_rcpf(d1.y * d2.y * d3y);
                }
            }
        }
    }

    // block reduction: wave shuffle -> LDS -> one atomic per block
    for (int off = 32; off > 0; off >>= 1)
        sum += __shfl_down(sum, off, 64);
    if ((tx & 63) == 0) bsum[tx >> 6] = sum;
    __syncthreads();
    if (tx == 0) {
        float tot = bsum[0] + bsum[1] + bsum[2] + bsum[3];
        atomicAdd(accp, (double)tot);
    }
}

// b2 = mean over 16 depth slices of img2, vectorized float4 (BW-bound).
__global__ __launch_bounds__(256) void depth_mean4_kernel(
    const float4* __restrict__ img2, float4* __restrict__ b2)
{
    const int per = SLICE / 4;                       // 65536 float4 per slice
    int idx = blockIdx.x * 256 + threadIdx.x;        // 0 .. 4*per-1
    int b = idx >> 16;
    int p = idx & (per - 1);
    const float4* src = img2 + (long)b * 16 * per + p;
    float sx = 0.f, sy = 0.f, sz = 0.f, sw = 0.f;
    #pragma unroll
    for (int d = 0; d < 16; d++) {
        float4 v = src[(long)d * per];
        sx += v.x; sy += v.y; sz += v.z; sw += v.w;
    }
    float4 o; o.x = sx * 0.0625f; o.y = sy * 0.0625f; o.z = sz * 0.0625f; o.w = sw * 0.0625f;
    b2[idx] = o;
}

__global__ void finalize_kernel(const double* __restrict__ acc, float* __restrict__ out)
{
    double loss3 = 1.0 - acc[0] / (64.0 * (double)SLICE);
    double loss2 = 1.0 - acc[1] / (4.0 * (double)SLICE);
    out[0] = (float)(loss3 + loss2);
}

extern "C" void kernel_launch(void* const* d_in, const int* in_sizes, int n_in,
                              void* d_out, int out_size, void* d_ws, size_t ws_size,
                              hipStream_t stream)
{
    const float* img1_3d = (const float*)d_in[0];   // [4,1,16,512,512] -> 64 slices
    const float* img1_2d = (const float*)d_in[1];   // [4,1,512,512]
    const float* img2    = (const float*)d_in[2];   // [4,1,16,512,512]
    float* out = (float*)d_out;

    double* acc = (double*)d_ws;                    // [0]=3D sum, [1]=2D sum
    float*  b2  = (float*)((char*)d_ws + 256);      // 4 MB depth-mean buffer

    // Gaussian weights, like cv2.getGaussianKernel(11, 1.5) in double.
    G11 gw;
    {
        double g[WSZ], s = 0.0;
        for (int i = 0; i < WSZ; i++) {
            double xx = (double)i - (WSZ - 1) / 2.0;
            g[i] = std::exp(-(xx * xx) / (2.0 * 1.5 * 1.5));
            s += g[i];
        }
        for (int i = 0; i < WSZ; i++) gw.w[i] = (float)(g[i] / s);
    }

    hipMemsetAsync(acc, 0, 2 * sizeof(double), stream);

    // depth mean of img2 -> b2 (68 MB, ~12 us)
    depth_mean4_kernel<<<(4 * SLICE / 4) / 256, 256, 0, stream>>>(
        (const float4*)img2, (float4*)b2);

    // merged SSIM: 1536 3D bands (64 slices x (16x22 + 8x20 rows))
    // + 256 2D bands (4 imgs x 64x8 rows) = 1792 blocks = exactly 7/CU.
    ssim_pk_kernel<<<1792, 256, 0, stream>>>(img1_3d, img2, img1_2d, b2, acc, gw);

    finalize_kernel<<<1, 1, 0, stream>>>(acc, out);
}